// Round 3
// baseline (139.523 us; speedup 1.0000x reference)
//
#include <hip/hip_runtime.h>
#include <hip/hip_bf16.h>

// Dilated-mask attention, B=2 H=16 S=2048 D=64, dilation=2 — single fused kernel.
// mask[i,j]=1 iff same parity; masked scores exactly 0 -> flash attn over
// same-parity keys with fixed m=0 (|scores/8| small), Z = l + 1024,
// out += Vsum_otherparity (computed in-kernel during V staging).

#define B_   2
#define H_   16
#define S_   2048
#define D_   64
#define SP_  1024
#define BQ   64
#define BK   64
#define NKT  (SP_ / BK)
#define LSTR 72     // LDS row stride in bf16: 144 B = 9*16 B, b128-aligned

// Q pre-scale: 1/sqrt(64) * log2(e)  ->  p = exp2(QK') = exp(QK/8)
#define QSCALE 0.180336884f

typedef __bf16 bf16x8 __attribute__((ext_vector_type(8)));
typedef float  f32x4  __attribute__((ext_vector_type(4)));

__global__ __launch_bounds__(256, 4) void attn_kernel(const float* __restrict__ Q,
                                                      const float* __restrict__ K,
                                                      const float* __restrict__ V,
                                                      float* __restrict__ out) {
    const int bh  = blockIdx.x;
    const int par = blockIdx.y;
    const int qt  = blockIdx.z;
    const int tid  = threadIdx.x;
    const int lane = tid & 63;
    const int wave = tid >> 6;       // wave w owns query rows [16w, 16w+16)
    const int l15  = lane & 15;
    const int quad = lane >> 4;

    __shared__ __align__(16) __bf16 q_s[BQ][LSTR];
    __shared__ __align__(16) __bf16 k_s[BK][LSTR];
    __shared__ __align__(16) __bf16 v_s[D_][LSTR];     // V^T: [d][key]
    // P strip per wave, swizzled: P[m][n] at [m][(n + 16*(m>>2)) & 63]
    __shared__ __align__(16) __bf16 p_s[4][16][64];
    __shared__ float vo_red[4][64];                    // opp-parity Vsum partials

    const size_t base = (size_t)bh * S_ * D_;
    const float* Qb = Q + base;
    const float* Kb = K + base;
    const float* Vb = V + base;
    const int vofs = (par == 0) ? D_ : -D_;            // opp-parity row offset (floats)

    // ---- stage Q tile (rows par + 2*(qt*64 + r)), pre-scaled, b128 writes
    #pragma unroll
    for (int i = 0; i < 2; ++i) {
        const int f = (i << 8) + tid;            // 0..511
        const int r = f >> 3, c8 = f & 7;
        const float* src = Qb + (size_t)(par + 2 * (qt * BQ + r)) * D_ + c8 * 8;
        const float4 a = *(const float4*)src;
        const float4 b = *(const float4*)(src + 4);
        bf16x8 w;
        w[0] = (__bf16)(a.x * QSCALE); w[1] = (__bf16)(a.y * QSCALE);
        w[2] = (__bf16)(a.z * QSCALE); w[3] = (__bf16)(a.w * QSCALE);
        w[4] = (__bf16)(b.x * QSCALE); w[5] = (__bf16)(b.y * QSCALE);
        w[6] = (__bf16)(b.z * QSCALE); w[7] = (__bf16)(b.w * QSCALE);
        *(bf16x8*)&q_s[r][c8 * 8] = w;
    }

    // ---- prefetch registers (tile kt+1 loads issued during tile kt compute)
    float4 pk[2][2];
    float  pv[2][8], pvo[2][8];

    auto issue_loads = [&](int kt) {
        #pragma unroll
        for (int i = 0; i < 2; ++i) {
            const int f = (i << 8) + tid;
            const int r = f >> 3, c8 = f & 7;
            const float* ksrc = Kb + (size_t)(par + 2 * (kt * BK + r)) * D_ + c8 * 8;
            pk[i][0] = *(const float4*)ksrc;
            pk[i][1] = *(const float4*)(ksrc + 4);
        }
        #pragma unroll
        for (int i = 0; i < 2; ++i) {
            const int r0 = (wave + 4 * i) << 3;
            const float* vsrc = Vb + (size_t)(par + 2 * (kt * BK + r0)) * D_ + lane;
            #pragma unroll
            for (int j = 0; j < 8; ++j) {
                pv[i][j]  = vsrc[(size_t)(2 * j) * D_];
                pvo[i][j] = vsrc[(size_t)(2 * j) * D_ + vofs];
            }
        }
    };

    issue_loads(0);

    f32x4 acc[4];
    #pragma unroll
    for (int nt = 0; nt < 4; ++nt) acc[nt] = (f32x4){0.f, 0.f, 0.f, 0.f};
    float l_acc[4] = {0.f, 0.f, 0.f, 0.f};
    float vo = 0.f;                  // opp-parity Vsum partial, column d = lane

    const int q0 = wave * 16;

    for (int kt = 0; kt < NKT; ++kt) {
        // ---- write prefetched tile to LDS (K row-major, V transposed)
        #pragma unroll
        for (int i = 0; i < 2; ++i) {
            const int f = (i << 8) + tid;
            const int r = f >> 3, c8 = f & 7;
            bf16x8 w;
            w[0] = (__bf16)pk[i][0].x; w[1] = (__bf16)pk[i][0].y;
            w[2] = (__bf16)pk[i][0].z; w[3] = (__bf16)pk[i][0].w;
            w[4] = (__bf16)pk[i][1].x; w[5] = (__bf16)pk[i][1].y;
            w[6] = (__bf16)pk[i][1].z; w[7] = (__bf16)pk[i][1].w;
            *(bf16x8*)&k_s[r][c8 * 8] = w;
        }
        #pragma unroll
        for (int i = 0; i < 2; ++i) {
            const int r0 = (wave + 4 * i) << 3;
            bf16x8 w;
            #pragma unroll
            for (int j = 0; j < 8; ++j) w[j] = (__bf16)pv[i][j];
            *(bf16x8*)&v_s[lane][r0] = w;
            vo += ((pvo[i][0] + pvo[i][1]) + (pvo[i][2] + pvo[i][3]))
                + ((pvo[i][4] + pvo[i][5]) + (pvo[i][6] + pvo[i][7]));
        }
        __syncthreads();

        // ---- issue next tile's global loads (latency hidden by compute below)
        if (kt + 1 < NKT) issue_loads(kt + 1);

        // ---- S' = (Q*QSCALE) K^T
        f32x4 sc[4];
        #pragma unroll
        for (int nt = 0; nt < 4; ++nt) sc[nt] = (f32x4){0.f, 0.f, 0.f, 0.f};
        #pragma unroll
        for (int ks = 0; ks < 2; ++ks) {
            const bf16x8 a = *(const bf16x8*)&q_s[q0 + l15][ks * 32 + quad * 8];
            #pragma unroll
            for (int nt = 0; nt < 4; ++nt) {
                const bf16x8 b = *(const bf16x8*)&k_s[nt * 16 + l15][ks * 32 + quad * 8];
                sc[nt] = __builtin_amdgcn_mfma_f32_16x16x32_bf16(a, b, sc[nt], 0, 0, 0);
            }
        }

        // ---- p = exp2(s'), accumulate per-lane l, write P strip (swizzled)
        #pragma unroll
        for (int nt = 0; nt < 4; ++nt) {
            const int colw = ((((nt + quad) & 3) << 4) + l15);
            #pragma unroll
            for (int r = 0; r < 4; ++r) {
                const float p = exp2f(sc[nt][r]);
                l_acc[r] += p;
                p_s[wave][quad * 4 + r][colw] = (__bf16)p;
            }
        }

        // ---- O += P V
        #pragma unroll
        for (int ks = 0; ks < 2; ++ks) {
            const int col0 = ((((2 * ks + (quad >> 1) + (l15 >> 2)) & 3) << 4)
                              + ((quad & 1) << 3));
            const bf16x8 pa = *(const bf16x8*)&p_s[wave][l15][col0];
            #pragma unroll
            for (int nt = 0; nt < 4; ++nt) {
                const bf16x8 bv = *(const bf16x8*)&v_s[nt * 16 + l15][ks * 32 + quad * 8];
                acc[nt] = __builtin_amdgcn_mfma_f32_16x16x32_bf16(pa, bv, acc[nt], 0, 0, 0);
            }
        }
        __syncthreads();   // tile fully consumed; LDS reusable
    }

    // ---- reduce opp-parity Vsum across waves
    vo_red[wave][lane] = vo;
    __syncthreads();

    // ---- epilogue: l reduction, masked-key correction (weight 1 each)
    float rz[4];
    #pragma unroll
    for (int r = 0; r < 4; ++r) {
        float s = l_acc[r];
        #pragma unroll
        for (int off = 1; off < 16; off <<= 1) s += __shfl_xor(s, off);
        rz[r] = 1.0f / (s + 1024.0f);
    }
    #pragma unroll
    for (int nt = 0; nt < 4; ++nt) {
        const int d = nt * 16 + l15;
        const float vso = (vo_red[0][d] + vo_red[1][d]) + (vo_red[2][d] + vo_red[3][d]);
        #pragma unroll
        for (int r = 0; r < 4; ++r) {
            const int qg = par + 2 * (qt * BQ + q0 + quad * 4 + r);
            out[base + (size_t)qg * D_ + d] = (acc[nt][r] + vso) * rz[r];
        }
    }
}

extern "C" void kernel_launch(void* const* d_in, const int* in_sizes, int n_in,
                              void* d_out, int out_size, void* d_ws, size_t ws_size,
                              hipStream_t stream) {
    const float* Q = (const float*)d_in[0];
    const float* K = (const float*)d_in[1];
    const float* V = (const float*)d_in[2];
    float* out = (float*)d_out;
    attn_kernel<<<dim3(B_ * H_, 2, SP_ / BQ), dim3(256), 0, stream>>>(Q, K, V, out);
}

// Round 4
// 128.669 us; speedup vs baseline: 1.0844x; 1.0844x over previous
//
#include <hip/hip_runtime.h>
#include <hip/hip_bf16.h>

// Dilated-mask attention, B=2 H=16 S=2048 D=64, dilation=2 — single fused kernel.
// mask[i,j]=1 iff same parity; masked scores exactly 0 -> flash attn over
// same-parity keys with fixed m=0 (|scores/8| small), Z = l + 1024,
// out += Vsum_otherparity (accumulated during V staging, L2-warm loads).
//
// Structure: BQ=128 (grid 512 = 2 blocks/CU), LDS-double-buffered K/V with a
// single barrier per K-tile: loads(kt+1) -> compute(kt) -> ds_write(kt+1) ->
// barrier. launch_bounds(256,2) keeps the 48 prefetch regs un-spilled (R3's
// failure was spilling under the (256,4) 128-VGPR cap).

#define B_   2
#define H_   16
#define S_   2048
#define D_   64
#define SP_  1024
#define BQ   128
#define BK   64
#define NKT  (SP_ / BK)

// Q pre-scale: 1/sqrt(64) * log2(e)  ->  p = exp2(QK') = exp(QK/8)
#define QSCALE 0.180336884f

typedef __bf16 bf16x8 __attribute__((ext_vector_type(8)));
typedef float  f32x4  __attribute__((ext_vector_type(4)));

// XOR-swizzled element offset inside a 64-elem (128 B) row: 16 B chunk c8 of
// row r lands at chunk c8^(r&7) -> no padding, and both the staging b128
// writes and the frag b128 reads are 2-way-per-bank (free) by construction.
#define KSW(r, c8) ((((c8) ^ ((r) & 7)) << 3))

__global__ __launch_bounds__(256, 2) void attn_kernel(const float* __restrict__ Q,
                                                      const float* __restrict__ K,
                                                      const float* __restrict__ V,
                                                      float* __restrict__ out) {
    const int bh  = blockIdx.x;
    const int par = blockIdx.y;
    const int qt  = blockIdx.z;
    const int tid  = threadIdx.x;
    const int lane = tid & 63;
    const int wave = tid >> 6;       // wave w owns query rows [32w, 32w+32)
    const int l15  = lane & 15;
    const int quad = lane >> 4;

    __shared__ __align__(16) __bf16 kbuf[2][BK][64];   // 16 KB, xor-swizzled
    __shared__ __align__(16) __bf16 vbuf[2][D_][64];   // 16 KB, V^T, xor-swizzled
    __shared__ __align__(16) __bf16 p_s[4][16][64];    // 8 KB, per-wave P strip
    // total 40 KB -> 2 blocks/CU at launch_bounds(256,2)

    const size_t base = (size_t)bh * S_ * D_;
    const float* Qb = Q + base;
    const float* Kb = K + base;
    const float* Vb = V + base;
    const int vofs = (par == 0) ? D_ : -D_;            // opp-parity row offset

    // ---- Q fragments straight to registers (one-time, no LDS round trip)
    bf16x8 qf[2][2];
    #pragma unroll
    for (int mt = 0; mt < 2; ++mt) {
        const int qrow = qt * BQ + wave * 32 + mt * 16 + l15;
        const float* qsrc = Qb + (size_t)(par + 2 * qrow) * D_ + quad * 8;
        #pragma unroll
        for (int ks = 0; ks < 2; ++ks) {
            const float4 a = *(const float4*)(qsrc + ks * 32);
            const float4 b = *(const float4*)(qsrc + ks * 32 + 4);
            bf16x8 w;
            w[0] = (__bf16)(a.x * QSCALE); w[1] = (__bf16)(a.y * QSCALE);
            w[2] = (__bf16)(a.z * QSCALE); w[3] = (__bf16)(a.w * QSCALE);
            w[4] = (__bf16)(b.x * QSCALE); w[5] = (__bf16)(b.y * QSCALE);
            w[6] = (__bf16)(b.z * QSCALE); w[7] = (__bf16)(b.w * QSCALE);
            qf[mt][ks] = w;
        }
    }

    // staging decomposition: K: thread covers rows i*32+(tid>>3), chunk tid&7;
    //                        V: column `lane`, key-chunks wave and wave+4.
    const int kr0 = tid >> 3;        // K row for i=0 (i=1: +32)
    const int kc8 = tid & 7;         // K 16B chunk

    float4 pka[2], pkb[2];           // K prefetch
    float  pv[16], pvo[16];          // V / opp-V prefetch

    // ---- prologue: load + stage tile 0 into buffer 0
    #pragma unroll
    for (int i = 0; i < 2; ++i) {
        const int r = i * 32 + kr0;
        const float* ksrc = Kb + (size_t)(par + 2 * r) * D_ + kc8 * 8;
        pka[i] = *(const float4*)ksrc;
        pkb[i] = *(const float4*)(ksrc + 4);
    }
    #pragma unroll
    for (int i = 0; i < 2; ++i) {
        const int c = wave + 4 * i;
        const float* vsrc = Vb + (size_t)(par + 2 * (c * 8)) * D_ + lane;
        #pragma unroll
        for (int j = 0; j < 8; ++j) {
            pv [i * 8 + j] = vsrc[(size_t)(2 * j) * D_];
            pvo[i * 8 + j] = vsrc[(size_t)(2 * j) * D_ + vofs];
        }
    }

    float vo = 0.f;                  // opp-parity Vsum partial, column d = lane
    #pragma unroll
    for (int i = 0; i < 2; ++i) {
        const int r = i * 32 + kr0;
        bf16x8 w;
        w[0] = (__bf16)pka[i].x; w[1] = (__bf16)pka[i].y;
        w[2] = (__bf16)pka[i].z; w[3] = (__bf16)pka[i].w;
        w[4] = (__bf16)pkb[i].x; w[5] = (__bf16)pkb[i].y;
        w[6] = (__bf16)pkb[i].z; w[7] = (__bf16)pkb[i].w;
        *(bf16x8*)&kbuf[0][r][KSW(r, kc8)] = w;
    }
    #pragma unroll
    for (int i = 0; i < 2; ++i) {
        const int c = wave + 4 * i;
        bf16x8 w;
        #pragma unroll
        for (int j = 0; j < 8; ++j) w[j] = (__bf16)pv[i * 8 + j];
        *(bf16x8*)&vbuf[0][lane][KSW(lane, c)] = w;
        vo += ((pvo[i*8+0] + pvo[i*8+1]) + (pvo[i*8+2] + pvo[i*8+3]))
            + ((pvo[i*8+4] + pvo[i*8+5]) + (pvo[i*8+6] + pvo[i*8+7]));
    }
    __syncthreads();

    f32x4 acc[2][4];
    #pragma unroll
    for (int mt = 0; mt < 2; ++mt)
        #pragma unroll
        for (int nt = 0; nt < 4; ++nt) acc[mt][nt] = (f32x4){0.f, 0.f, 0.f, 0.f};
    float l_acc[2][4] = {{0.f,0.f,0.f,0.f},{0.f,0.f,0.f,0.f}};

    for (int kt = 0; kt < NKT; ++kt) {
        const int cur = kt & 1;
        const bool pf = (kt + 1 < NKT);

        // ---- issue tile kt+1 global loads (latency overlaps compute below)
        if (pf) {
            #pragma unroll
            for (int i = 0; i < 2; ++i) {
                const int r = i * 32 + kr0;
                const float* ksrc = Kb + (size_t)(par + 2 * ((kt + 1) * BK + r)) * D_ + kc8 * 8;
                pka[i] = *(const float4*)ksrc;
                pkb[i] = *(const float4*)(ksrc + 4);
            }
            #pragma unroll
            for (int i = 0; i < 2; ++i) {
                const int c = wave + 4 * i;
                const float* vsrc = Vb + (size_t)(par + 2 * ((kt + 1) * BK + c * 8)) * D_ + lane;
                #pragma unroll
                for (int j = 0; j < 8; ++j) {
                    pv [i * 8 + j] = vsrc[(size_t)(2 * j) * D_];
                    pvo[i * 8 + j] = vsrc[(size_t)(2 * j) * D_ + vofs];
                }
            }
        }

        // ---- compute tile kt from buffer cur
        {
            const __bf16 (*kb)[64] = kbuf[cur];
            const __bf16 (*vb)[64] = vbuf[cur];
            #pragma unroll
            for (int mt = 0; mt < 2; ++mt) {
                f32x4 sc[4];
                #pragma unroll
                for (int nt = 0; nt < 4; ++nt) sc[nt] = (f32x4){0.f, 0.f, 0.f, 0.f};
                #pragma unroll
                for (int ks = 0; ks < 2; ++ks) {
                    const bf16x8 a = qf[mt][ks];
                    #pragma unroll
                    for (int nt = 0; nt < 4; ++nt) {
                        const int R = nt * 16 + l15;
                        const bf16x8 b = *(const bf16x8*)&kb[R][KSW(R, ks * 4 + quad)];
                        sc[nt] = __builtin_amdgcn_mfma_f32_16x16x32_bf16(a, b, sc[nt], 0, 0, 0);
                    }
                }
                // p = exp2(s'), per-lane l, P strip (swizzled, per-wave private:
                // DS pipe is in-order per wave, so mt=1 writes can't pass mt=0 reads)
                #pragma unroll
                for (int nt = 0; nt < 4; ++nt) {
                    const int colw = ((((nt + quad) & 3) << 4) + l15);
                    #pragma unroll
                    for (int r = 0; r < 4; ++r) {
                        const float p = exp2f(sc[nt][r]);
                        l_acc[mt][r] += p;
                        p_s[wave][quad * 4 + r][colw] = (__bf16)p;
                    }
                }
                #pragma unroll
                for (int ks = 0; ks < 2; ++ks) {
                    const int col0 = ((((2 * ks + (quad >> 1) + (l15 >> 2)) & 3) << 4)
                                      + ((quad & 1) << 3));
                    const bf16x8 pa = *(const bf16x8*)&p_s[wave][l15][col0];
                    #pragma unroll
                    for (int nt = 0; nt < 4; ++nt) {
                        const int R = nt * 16 + l15;
                        const bf16x8 bv = *(const bf16x8*)&vb[R][KSW(R, ks * 4 + quad)];
                        acc[mt][nt] = __builtin_amdgcn_mfma_f32_16x16x32_bf16(pa, bv, acc[mt][nt], 0, 0, 0);
                    }
                }
            }
        }

        // ---- convert + stage tile kt+1 into the other buffer
        if (pf) {
            const int nxt = 1 - cur;
            #pragma unroll
            for (int i = 0; i < 2; ++i) {
                const int r = i * 32 + kr0;
                bf16x8 w;
                w[0] = (__bf16)pka[i].x; w[1] = (__bf16)pka[i].y;
                w[2] = (__bf16)pka[i].z; w[3] = (__bf16)pka[i].w;
                w[4] = (__bf16)pkb[i].x; w[5] = (__bf16)pkb[i].y;
                w[6] = (__bf16)pkb[i].z; w[7] = (__bf16)pkb[i].w;
                *(bf16x8*)&kbuf[nxt][r][KSW(r, kc8)] = w;
            }
            #pragma unroll
            for (int i = 0; i < 2; ++i) {
                const int c = wave + 4 * i;
                bf16x8 w;
                #pragma unroll
                for (int j = 0; j < 8; ++j) w[j] = (__bf16)pv[i * 8 + j];
                *(bf16x8*)&vbuf[nxt][lane][KSW(lane, c)] = w;
                vo += ((pvo[i*8+0] + pvo[i*8+1]) + (pvo[i*8+2] + pvo[i*8+3]))
                    + ((pvo[i*8+4] + pvo[i*8+5]) + (pvo[i*8+6] + pvo[i*8+7]));
            }
        }
        __syncthreads();   // writes to nxt visible; reads of cur complete
    }

    // ---- cross-wave reduction of opp-parity Vsum (p_s is dead -> reuse)
    float* vred = (float*)p_s;
    vred[wave * 64 + lane] = vo;
    __syncthreads();

    // ---- epilogue: l reduction (over n: nt folded already, l15 via shfl_xor)
    float rz[2][4];
    #pragma unroll
    for (int mt = 0; mt < 2; ++mt)
        #pragma unroll
        for (int r = 0; r < 4; ++r) {
            float s = l_acc[mt][r];
            #pragma unroll
            for (int off = 1; off < 16; off <<= 1) s += __shfl_xor(s, off);
            rz[mt][r] = 1.0f / (s + 1024.0f);
        }

    #pragma unroll
    for (int nt = 0; nt < 4; ++nt) {
        const int d = nt * 16 + l15;
        const float vso = (vred[d] + vred[64 + d]) + (vred[128 + d] + vred[192 + d]);
        #pragma unroll
        for (int mt = 0; mt < 2; ++mt) {
            #pragma unroll
            for (int r = 0; r < 4; ++r) {
                const int qg = par + 2 * (qt * BQ + wave * 32 + mt * 16 + quad * 4 + r);
                out[base + (size_t)qg * D_ + d] = (acc[mt][nt][r] + vso) * rz[mt][r];
            }
        }
    }
}

extern "C" void kernel_launch(void* const* d_in, const int* in_sizes, int n_in,
                              void* d_out, int out_size, void* d_ws, size_t ws_size,
                              hipStream_t stream) {
    const float* Q = (const float*)d_in[0];
    const float* K = (const float*)d_in[1];
    const float* V = (const float*)d_in[2];
    float* out = (float*)d_out;
    attn_kernel<<<dim3(B_ * H_, 2, SP_ / BQ), dim3(256), 0, stream>>>(Q, K, V, out);
}

// Round 5
// 114.677 us; speedup vs baseline: 1.2167x; 1.1220x over previous
//
#include <hip/hip_runtime.h>
#include <hip/hip_bf16.h>

// Dilated-mask attention, B=2 H=16 S=2048 D=64, dilation=2 — single fused kernel.
// mask[i,j]=1 iff same parity; masked scores exactly 0 -> flash attn over
// same-parity keys with fixed m=0 (|scores/8| small), Z = l + 1024,
// out += Vsum_otherparity (accumulated during V staging, L2-warm loads).
//
// R5: 512-thread blocks (8 waves, BQ=128) -> 16 waves/CU (2 blocks), halved
// per-thread prefetch state (24 floats) under __launch_bounds__(512,4)'s
// 128-VGPR cap. Single barrier per K-tile, LDS dbuf, xor-swizzle (R4).
// exp via raw v_exp_f32.

#define B_   2
#define H_   16
#define S_   2048
#define D_   64
#define SP_  1024
#define BQ   128
#define BK   64
#define NKT  (SP_ / BK)
#define NW   8          // waves per block

// Q pre-scale: 1/sqrt(64) * log2(e)  ->  p = exp2(QK') = exp(QK/8)
#define QSCALE 0.180336884f

#if __has_builtin(__builtin_amdgcn_exp2f)
#define EXP2(x) __builtin_amdgcn_exp2f(x)
#else
#define EXP2(x) exp2f(x)
#endif

typedef __bf16 bf16x8 __attribute__((ext_vector_type(8)));
typedef float  f32x4  __attribute__((ext_vector_type(4)));

// XOR-swizzled element offset inside a 64-elem (128 B) row: 16 B chunk c8 of
// row r lands at chunk c8^(r&7) -> no padding; staging b128 writes and frag
// b128 reads are both conflict-free by construction.
#define KSW(r, c8) ((((c8) ^ ((r) & 7)) << 3))

__global__ __launch_bounds__(512, 4) void attn_kernel(const float* __restrict__ Q,
                                                      const float* __restrict__ K,
                                                      const float* __restrict__ V,
                                                      float* __restrict__ out) {
    const int bh  = blockIdx.x;
    const int par = blockIdx.y;
    const int qt  = blockIdx.z;
    const int tid  = threadIdx.x;
    const int lane = tid & 63;
    const int wave = tid >> 6;       // wave w owns query rows [16w, 16w+16)
    const int l15  = lane & 15;
    const int quad = lane >> 4;

    __shared__ __align__(16) __bf16 kbuf[2][BK][64];   // 16 KB, xor-swizzled
    __shared__ __align__(16) __bf16 vbuf[2][D_][64];   // 16 KB, V^T, xor-swizzled
    __shared__ __align__(16) __bf16 p_s[NW][16][64];   // 16 KB, per-wave P strip
    // total 48 KB -> 2 blocks/CU (96 KB), VGPR-capped at 128 via (512,4)

    const size_t base = (size_t)bh * S_ * D_;
    const float* Qb = Q + base;
    const float* Kb = K + base;
    const float* Vb = V + base;
    const int vofs = (par == 0) ? D_ : -D_;            // opp-parity row offset

    // ---- Q fragment straight to registers (one-time)
    bf16x8 qf[2];
    {
        const int qrow = qt * BQ + wave * 16 + l15;
        const float* qsrc = Qb + (size_t)(par + 2 * qrow) * D_ + quad * 8;
        #pragma unroll
        for (int ks = 0; ks < 2; ++ks) {
            const float4 a = *(const float4*)(qsrc + ks * 32);
            const float4 b = *(const float4*)(qsrc + ks * 32 + 4);
            bf16x8 w;
            w[0] = (__bf16)(a.x * QSCALE); w[1] = (__bf16)(a.y * QSCALE);
            w[2] = (__bf16)(a.z * QSCALE); w[3] = (__bf16)(a.w * QSCALE);
            w[4] = (__bf16)(b.x * QSCALE); w[5] = (__bf16)(b.y * QSCALE);
            w[6] = (__bf16)(b.z * QSCALE); w[7] = (__bf16)(b.w * QSCALE);
            qf[ks] = w;
        }
    }

    // staging decomposition (512 threads):
    //   K: thread covers row tid>>3 (0..63), 16B chunk tid&7 -> 2 float4 loads
    //   V: column `lane`, key-chunk `wave` (keys 8w..8w+7) -> 8+8 scalar loads
    const int kr  = tid >> 3;
    const int kc8 = tid & 7;

    float4 pka, pkb;                 // K prefetch
    float  pv[8], pvo[8];            // V / opp-V prefetch

    // ---- prologue: load + stage tile 0 into buffer 0
    {
        const float* ksrc = Kb + (size_t)(par + 2 * kr) * D_ + kc8 * 8;
        pka = *(const float4*)ksrc;
        pkb = *(const float4*)(ksrc + 4);
        const float* vsrc = Vb + (size_t)(par + 2 * (wave * 8)) * D_ + lane;
        #pragma unroll
        for (int j = 0; j < 8; ++j) {
            pv [j] = vsrc[(size_t)(2 * j) * D_];
            pvo[j] = vsrc[(size_t)(2 * j) * D_ + vofs];
        }
    }

    float vo = 0.f;                  // opp-parity Vsum partial, column d = lane
    {
        bf16x8 w;
        w[0] = (__bf16)pka.x; w[1] = (__bf16)pka.y;
        w[2] = (__bf16)pka.z; w[3] = (__bf16)pka.w;
        w[4] = (__bf16)pkb.x; w[5] = (__bf16)pkb.y;
        w[6] = (__bf16)pkb.z; w[7] = (__bf16)pkb.w;
        *(bf16x8*)&kbuf[0][kr][KSW(kr, kc8)] = w;
        bf16x8 wv;
        #pragma unroll
        for (int j = 0; j < 8; ++j) wv[j] = (__bf16)pv[j];
        *(bf16x8*)&vbuf[0][lane][KSW(lane, wave)] = wv;
        vo += ((pvo[0] + pvo[1]) + (pvo[2] + pvo[3]))
            + ((pvo[4] + pvo[5]) + (pvo[6] + pvo[7]));
    }
    __syncthreads();

    f32x4 acc[4];
    #pragma unroll
    for (int nt = 0; nt < 4; ++nt) acc[nt] = (f32x4){0.f, 0.f, 0.f, 0.f};
    float l_acc[4] = {0.f, 0.f, 0.f, 0.f};

    for (int kt = 0; kt < NKT; ++kt) {
        const int cur = kt & 1;
        const bool pf = (kt + 1 < NKT);

        // ---- issue tile kt+1 global loads (latency overlaps compute below)
        if (pf) {
            const float* ksrc = Kb + (size_t)(par + 2 * ((kt + 1) * BK + kr)) * D_ + kc8 * 8;
            pka = *(const float4*)ksrc;
            pkb = *(const float4*)(ksrc + 4);
            const float* vsrc = Vb + (size_t)(par + 2 * ((kt + 1) * BK + wave * 8)) * D_ + lane;
            #pragma unroll
            for (int j = 0; j < 8; ++j) {
                pv [j] = vsrc[(size_t)(2 * j) * D_];
                pvo[j] = vsrc[(size_t)(2 * j) * D_ + vofs];
            }
        }

        // ---- compute tile kt from buffer cur
        {
            const __bf16 (*kb)[64] = kbuf[cur];
            const __bf16 (*vb)[64] = vbuf[cur];
            f32x4 sc[4];
            #pragma unroll
            for (int nt = 0; nt < 4; ++nt) sc[nt] = (f32x4){0.f, 0.f, 0.f, 0.f};
            #pragma unroll
            for (int ks = 0; ks < 2; ++ks) {
                #pragma unroll
                for (int nt = 0; nt < 4; ++nt) {
                    const int R = nt * 16 + l15;
                    const bf16x8 b = *(const bf16x8*)&kb[R][KSW(R, ks * 4 + quad)];
                    sc[nt] = __builtin_amdgcn_mfma_f32_16x16x32_bf16(qf[ks], b, sc[nt], 0, 0, 0);
                }
            }
            // p = exp2(s'), per-lane l, P strip (swizzled; per-wave private,
            // DS pipe is in-order per wave so the b128 reads below are safe)
            #pragma unroll
            for (int nt = 0; nt < 4; ++nt) {
                const int colw = ((((nt + quad) & 3) << 4) + l15);
                #pragma unroll
                for (int r = 0; r < 4; ++r) {
                    const float p = EXP2(sc[nt][r]);
                    l_acc[r] += p;
                    p_s[wave][quad * 4 + r][colw] = (__bf16)p;
                }
            }
            #pragma unroll
            for (int ks = 0; ks < 2; ++ks) {
                const int col0 = ((((2 * ks + (quad >> 1) + (l15 >> 2)) & 3) << 4)
                                  + ((quad & 1) << 3));
                const bf16x8 pa = *(const bf16x8*)&p_s[wave][l15][col0];
                #pragma unroll
                for (int nt = 0; nt < 4; ++nt) {
                    const int R = nt * 16 + l15;
                    const bf16x8 bv = *(const bf16x8*)&vb[R][KSW(R, ks * 4 + quad)];
                    acc[nt] = __builtin_amdgcn_mfma_f32_16x16x32_bf16(pa, bv, acc[nt], 0, 0, 0);
                }
            }
        }

        // ---- convert + stage tile kt+1 into the other buffer
        if (pf) {
            const int nxt = 1 - cur;
            bf16x8 w;
            w[0] = (__bf16)pka.x; w[1] = (__bf16)pka.y;
            w[2] = (__bf16)pka.z; w[3] = (__bf16)pka.w;
            w[4] = (__bf16)pkb.x; w[5] = (__bf16)pkb.y;
            w[6] = (__bf16)pkb.z; w[7] = (__bf16)pkb.w;
            *(bf16x8*)&kbuf[nxt][kr][KSW(kr, kc8)] = w;
            bf16x8 wv;
            #pragma unroll
            for (int j = 0; j < 8; ++j) wv[j] = (__bf16)pv[j];
            *(bf16x8*)&vbuf[nxt][lane][KSW(lane, wave)] = wv;
            vo += ((pvo[0] + pvo[1]) + (pvo[2] + pvo[3]))
                + ((pvo[4] + pvo[5]) + (pvo[6] + pvo[7]));
        }
        __syncthreads();   // writes to nxt visible; reads of cur complete
    }

    // ---- cross-wave reduction of opp-parity Vsum (p_s is dead -> reuse)
    float* vred = (float*)p_s;
    vred[wave * 64 + lane] = vo;
    __syncthreads();

    // ---- epilogue: l reduction + masked-key correction (weight 1 each)
    float rz[4];
    #pragma unroll
    for (int r = 0; r < 4; ++r) {
        float s = l_acc[r];
        #pragma unroll
        for (int off = 1; off < 16; off <<= 1) s += __shfl_xor(s, off);
        rz[r] = 1.0f / (s + 1024.0f);
    }
    #pragma unroll
    for (int nt = 0; nt < 4; ++nt) {
        const int d = nt * 16 + l15;
        float vso = 0.f;
        #pragma unroll
        for (int w = 0; w < NW; ++w) vso += vred[w * 64 + d];
        #pragma unroll
        for (int r = 0; r < 4; ++r) {
            const int qg = par + 2 * (qt * BQ + wave * 16 + quad * 4 + r);
            out[base + (size_t)qg * D_ + d] = (acc[nt][r] + vso) * rz[r];
        }
    }
}

extern "C" void kernel_launch(void* const* d_in, const int* in_sizes, int n_in,
                              void* d_out, int out_size, void* d_ws, size_t ws_size,
                              hipStream_t stream) {
    const float* Q = (const float*)d_in[0];
    const float* K = (const float*)d_in[1];
    const float* V = (const float*)d_in[2];
    float* out = (float*)d_out;
    attn_kernel<<<dim3(B_ * H_, 2, SP_ / BQ), dim3(512), 0, stream>>>(Q, K, V, out);
}

// Round 6
// 113.805 us; speedup vs baseline: 1.2260x; 1.0077x over previous
//
#include <hip/hip_runtime.h>
#include <hip/hip_bf16.h>

// Dilated-mask attention, B=2 H=16 S=2048 D=64, dilation=2 — single fused kernel.
// mask[i,j]=1 iff same parity; masked scores exactly 0 -> flash attn over
// same-parity keys with fixed m=0, Z = l + 1024, out += Vsum_otherparity.
//
// R6: DS-throughput-targeted rewrite. Waves own 32 queries (halves per-query
// K/V LDS frag reads). QK computes S^T = K*Q^T (operand swap) so P exits with
// 4 consecutive KEYS per register column -> packed ds_write_b64 P^T staging
// (8 b64 w + 4 b128 r per wave-tile vs 16 scalar b16 + reads). Per-wave-tile
// DS issue: 8+8 b128 frags + 8 b64 + 4 b128 + 2 staging ~= 312 cyc for 32q.

#define B_   2
#define H_   16
#define S_   2048
#define D_   64
#define SP_  1024
#define BQ   128
#define BK   64
#define NKT  (SP_ / BK)
#define NW   4          // waves per block; each owns 32 queries

// Q pre-scale: 1/sqrt(64) * log2(e)  ->  p = exp2(QK') = exp(QK/8)
#define QSCALE 0.180336884f

#if __has_builtin(__builtin_amdgcn_exp2f)
#define EXP2(x) __builtin_amdgcn_exp2f(x)
#else
#define EXP2(x) exp2f(x)
#endif

typedef __bf16 bf16x8 __attribute__((ext_vector_type(8)));
typedef __bf16 bf16x4 __attribute__((ext_vector_type(4)));
typedef float  f32x4  __attribute__((ext_vector_type(4)));

// XOR-swizzled element offset inside a 64-elem (128 B) row: 16 B chunk c8 of
// row r lands at chunk c8^(r&7) -> staging b128 writes and frag b128 reads
// both conflict-free, no padding.
#define KSW(r, c8) ((((c8) ^ ((r) & 7)) << 3))

__global__ __launch_bounds__(256, 2) void attn_kernel(const float* __restrict__ Q,
                                                      const float* __restrict__ K,
                                                      const float* __restrict__ V,
                                                      float* __restrict__ out) {
    const int bh  = blockIdx.x;
    const int par = blockIdx.y;
    const int qt  = blockIdx.z;
    const int tid  = threadIdx.x;
    const int lane = tid & 63;
    const int wave = tid >> 6;       // wave w owns query rows [32w, 32w+32)
    const int l15  = lane & 15;
    const int quad = lane >> 4;

    __shared__ __align__(16) __bf16 kbuf[2][BK][64];   // 16 KB, xor-swizzled
    __shared__ __align__(16) __bf16 vbuf[2][D_][64];   // 16 KB, V^T, xor-swizzled
    __shared__ __align__(16) __bf16 pt[NW][32][64];    // 16 KB, per-wave P^T [q][key]
    // total 48 KB -> 2 blocks/CU; VGPR cap 256 via (256,2) (48-float prefetch ok)

    const size_t base = (size_t)bh * S_ * D_;
    const float* Qb = Q + base;
    const float* Kb = K + base;
    const float* Vb = V + base;
    const int vofs = (par == 0) ? D_ : -D_;            // opp-parity row offset

    // ---- Q as MFMA *B*-operand fragments (S^T = K·Q^T): B[n=query l15][k=d]
    bf16x8 qf[2][2];                 // [qt2][ks]
    #pragma unroll
    for (int qt2 = 0; qt2 < 2; ++qt2) {
        const int qrow = qt * BQ + wave * 32 + qt2 * 16 + l15;
        const float* qsrc = Qb + (size_t)(par + 2 * qrow) * D_ + quad * 8;
        #pragma unroll
        for (int ks = 0; ks < 2; ++ks) {
            const float4 a = *(const float4*)(qsrc + ks * 32);
            const float4 b = *(const float4*)(qsrc + ks * 32 + 4);
            bf16x8 w;
            w[0] = (__bf16)(a.x * QSCALE); w[1] = (__bf16)(a.y * QSCALE);
            w[2] = (__bf16)(a.z * QSCALE); w[3] = (__bf16)(a.w * QSCALE);
            w[4] = (__bf16)(b.x * QSCALE); w[5] = (__bf16)(b.y * QSCALE);
            w[6] = (__bf16)(b.z * QSCALE); w[7] = (__bf16)(b.w * QSCALE);
            qf[qt2][ks] = w;
        }
    }

    // staging decomposition (256 threads):
    //   K: rows i*32+(tid>>3), chunk tid&7; V: column lane, key-chunks wave, wave+4
    const int kr0 = tid >> 3;
    const int kc8 = tid & 7;

    float4 pka[2], pkb[2];
    float  pv[16], pvo[16];

    auto issue_loads = [&](int kt) {
        #pragma unroll
        for (int i = 0; i < 2; ++i) {
            const int r = i * 32 + kr0;
            const float* ksrc = Kb + (size_t)(par + 2 * (kt * BK + r)) * D_ + kc8 * 8;
            pka[i] = *(const float4*)ksrc;
            pkb[i] = *(const float4*)(ksrc + 4);
        }
        #pragma unroll
        for (int i = 0; i < 2; ++i) {
            const int c = wave + 4 * i;
            const float* vsrc = Vb + (size_t)(par + 2 * (kt * BK + c * 8)) * D_ + lane;
            #pragma unroll
            for (int j = 0; j < 8; ++j) {
                pv [i * 8 + j] = vsrc[(size_t)(2 * j) * D_];
                pvo[i * 8 + j] = vsrc[(size_t)(2 * j) * D_ + vofs];
            }
        }
    };

    float vo = 0.f;                  // opp-parity Vsum partial, column d = lane
    auto stage = [&](int buf) {
        #pragma unroll
        for (int i = 0; i < 2; ++i) {
            const int r = i * 32 + kr0;
            bf16x8 w;
            w[0] = (__bf16)pka[i].x; w[1] = (__bf16)pka[i].y;
            w[2] = (__bf16)pka[i].z; w[3] = (__bf16)pka[i].w;
            w[4] = (__bf16)pkb[i].x; w[5] = (__bf16)pkb[i].y;
            w[6] = (__bf16)pkb[i].z; w[7] = (__bf16)pkb[i].w;
            *(bf16x8*)&kbuf[buf][r][KSW(r, kc8)] = w;
        }
        #pragma unroll
        for (int i = 0; i < 2; ++i) {
            const int c = wave + 4 * i;
            bf16x8 w;
            #pragma unroll
            for (int j = 0; j < 8; ++j) w[j] = (__bf16)pv[i * 8 + j];
            *(bf16x8*)&vbuf[buf][lane][KSW(lane, c)] = w;
            vo += ((pvo[i*8+0] + pvo[i*8+1]) + (pvo[i*8+2] + pvo[i*8+3]))
                + ((pvo[i*8+4] + pvo[i*8+5]) + (pvo[i*8+6] + pvo[i*8+7]));
        }
    };

    issue_loads(0);
    stage(0);
    __syncthreads();

    f32x4 acc[2][4];                 // [qt2][dt], C-layout: l15=d, rows=query
    #pragma unroll
    for (int q2 = 0; q2 < 2; ++q2)
        #pragma unroll
        for (int dt = 0; dt < 4; ++dt) acc[q2][dt] = (f32x4){0.f, 0.f, 0.f, 0.f};
    float l_acc[2] = {0.f, 0.f};     // per-lane partial Z for query l15 (per qt2)

    for (int kt = 0; kt < NKT; ++kt) {
        const int cur = kt & 1;
        const bool pf = (kt + 1 < NKT);

        if (pf) issue_loads(kt + 1);   // latency overlaps compute below

        const __bf16 (*kb)[64] = kbuf[cur];
        const __bf16 (*vb)[64] = vbuf[cur];

        // ---- K A-fragments (read once, reused for both qt2)
        bf16x8 ka[2][4];             // [ks][kt4]
        #pragma unroll
        for (int ks = 0; ks < 2; ++ks)
            #pragma unroll
            for (int kt4 = 0; kt4 < 4; ++kt4) {
                const int R = kt4 * 16 + l15;
                ka[ks][kt4] = *(const bf16x8*)&kb[R][KSW(R, ks * 4 + quad)];
            }

        // ---- S^T = K·Q^T, then p=exp2, pack 4 consecutive keys -> ds_write_b64
        #pragma unroll
        for (int qt2 = 0; qt2 < 2; ++qt2) {
            f32x4 st[4];
            #pragma unroll
            for (int kt4 = 0; kt4 < 4; ++kt4) st[kt4] = (f32x4){0.f, 0.f, 0.f, 0.f};
            #pragma unroll
            for (int ks = 0; ks < 2; ++ks)
                #pragma unroll
                for (int kt4 = 0; kt4 < 4; ++kt4)
                    st[kt4] = __builtin_amdgcn_mfma_f32_16x16x32_bf16(
                        ka[ks][kt4], qf[qt2][ks], st[kt4], 0, 0, 0);
            // lane (quad,l15) holds keys kt4*16+quad*4+r of query l15
            #pragma unroll
            for (int kt4 = 0; kt4 < 4; ++kt4) {
                bf16x4 w;
                #pragma unroll
                for (int r = 0; r < 4; ++r) {
                    const float p = EXP2(st[kt4][r]);
                    l_acc[qt2] += p;
                    w[r] = (__bf16)p;
                }
                // semantic elem = key = kt4*16+quad*4+r; chunk = kt4*2+(quad>>1),
                // 8B-half = quad&1; xor-swizzle chunk by row&7 (row = qt2*16+l15)
                const int ch = (kt4 * 2 + (quad >> 1)) ^ (l15 & 7);
                *(bf16x4*)&pt[wave][qt2 * 16 + l15][ch * 8 + (quad & 1) * 4] = w;
            }
        }

        // ---- O = P V: A = P^T rows (m=query), B = V^T (n=d)
        #pragma unroll
        for (int ks = 0; ks < 2; ++ks) {
            bf16x8 pa[2];
            #pragma unroll
            for (int qt2 = 0; qt2 < 2; ++qt2)
                pa[qt2] = *(const bf16x8*)
                    &pt[wave][qt2 * 16 + l15][KSW(l15, ks * 4 + quad)];
            #pragma unroll
            for (int dt = 0; dt < 4; ++dt) {
                const int Rv = dt * 16 + l15;
                const bf16x8 bv = *(const bf16x8*)&vb[Rv][KSW(Rv, ks * 4 + quad)];
                acc[0][dt] = __builtin_amdgcn_mfma_f32_16x16x32_bf16(pa[0], bv, acc[0][dt], 0, 0, 0);
                acc[1][dt] = __builtin_amdgcn_mfma_f32_16x16x32_bf16(pa[1], bv, acc[1][dt], 0, 0, 0);
            }
        }

        if (pf) stage(1 - cur);
        __syncthreads();
    }

    // ---- cross-wave reduction of opp-parity Vsum (pt is dead -> reuse)
    float* vred = (float*)pt;
    vred[wave * 64 + lane] = vo;
    __syncthreads();

    // ---- epilogue: Z per query; rz broadcast to acc rows via shfl
    float rz[2][4];
    #pragma unroll
    for (int qt2 = 0; qt2 < 2; ++qt2) {
        float lf = l_acc[qt2];
        lf += __shfl_xor(lf, 16);
        lf += __shfl_xor(lf, 32);    // all quads now hold Z-partial for query l15
        #pragma unroll
        for (int r = 0; r < 4; ++r) {
            const float lr = __shfl(lf, quad * 4 + r);   // query row quad*4+r
            rz[qt2][r] = 1.0f / (lr + 1024.0f);
        }
    }
    #pragma unroll
    for (int dt = 0; dt < 4; ++dt) {
        const int d = dt * 16 + l15;
        const float vso = (vred[d] + vred[64 + d]) + (vred[128 + d] + vred[192 + d]);
        #pragma unroll
        for (int qt2 = 0; qt2 < 2; ++qt2)
            #pragma unroll
            for (int r = 0; r < 4; ++r) {
                const int qg = par + 2 * (qt * BQ + wave * 32 + qt2 * 16 + quad * 4 + r);
                out[base + (size_t)qg * D_ + d] = (acc[qt2][dt][r] + vso) * rz[qt2][r];
            }
    }
}

extern "C" void kernel_launch(void* const* d_in, const int* in_sizes, int n_in,
                              void* d_out, int out_size, void* d_ws, size_t ws_size,
                              hipStream_t stream) {
    const float* Q = (const float*)d_in[0];
    const float* K = (const float*)d_in[1];
    const float* V = (const float*)d_in[2];
    float* out = (float*)d_out;
    attn_kernel<<<dim3(B_ * H_, 2, SP_ / BQ), dim3(256), 0, stream>>>(Q, K, V, out);
}

// Round 7
// 112.157 us; speedup vs baseline: 1.2440x; 1.0147x over previous
//
#include <hip/hip_runtime.h>
#include <hip/hip_bf16.h>

// Dilated-mask attention, B=2 H=16 S=2048 D=64, dilation=2 — single fused kernel.
// mask[i,j]=1 iff same parity; masked scores exactly 0 -> flash attn over
// same-parity keys with fixed m=0, Z = l + 1024, out += Vsum_otherparity.
//
// R7: direct-P PV. st = K·Q^T exits QK in C-layout [m=key=quad*4+r][n=query=l15],
// which IS the B-operand layout of mfma_f32_16x16x16_bf16 (B[k=quad*4+j][n=l15]).
// exp+cvt in registers feeds PV directly: O^T += V^T(A,b64 from vbuf)·P(B,regs).
// Removes the per-tile P LDS round-trip (8 b64 w + 4 b128 r + lgkm hop on the
// critical chain). Output transposed -> one-time per-wave epilogue LDS transpose.

#define B_   2
#define H_   16
#define S_   2048
#define D_   64
#define SP_  1024
#define BQ   128
#define BK   64
#define NKT  (SP_ / BK)
#define NW   4          // waves per block; each owns 32 queries

// Q pre-scale: 1/sqrt(64) * log2(e)  ->  p = exp2(QK') = exp(QK/8)
#define QSCALE 0.180336884f

#if __has_builtin(__builtin_amdgcn_exp2f)
#define EXP2(x) __builtin_amdgcn_exp2f(x)
#else
#define EXP2(x) exp2f(x)
#endif

typedef __bf16 bf16x8 __attribute__((ext_vector_type(8)));
typedef __bf16 bf16x4 __attribute__((ext_vector_type(4)));
typedef float  f32x4  __attribute__((ext_vector_type(4)));
typedef short  s16x4  __attribute__((ext_vector_type(4)));

static __device__ __forceinline__ f32x4 mfma16(bf16x4 a, bf16x4 b, f32x4 c) {
    return __builtin_amdgcn_mfma_f32_16x16x16bf16_1k(
        __builtin_bit_cast(s16x4, a), __builtin_bit_cast(s16x4, b), c, 0, 0, 0);
}

// XOR-swizzled element offset inside a 64-elem (128 B) row: 16 B chunk c8 of
// row r lands at chunk c8^(r&7). Staging b128 writes, K b128 frag reads, and
// V^T b64 A-frag reads all <=2-way (free).
#define KSW(r, c8) ((((c8) ^ ((r) & 7)) << 3))

__global__ __launch_bounds__(256, 2) void attn_kernel(const float* __restrict__ Q,
                                                      const float* __restrict__ K,
                                                      const float* __restrict__ V,
                                                      float* __restrict__ out) {
    const int bh  = blockIdx.x;
    const int par = blockIdx.y;
    const int qt  = blockIdx.z;
    const int tid  = threadIdx.x;
    const int lane = tid & 63;
    const int wave = tid >> 6;       // wave w owns query rows [32w, 32w+32)
    const int l15  = lane & 15;
    const int quad = lane >> 4;

    // arena: [0,16K) kbuf[2][64][64], [16K,32K) vbuf[2][64][64] (V^T),
    // [32K,33K) vred. Epilogue reuses [0,17408) as per-wave f32 transpose tiles.
    __shared__ __align__(16) char arena[33792];
    __bf16 (*kbuf)[BK][64] = (__bf16 (*)[BK][64])arena;
    __bf16 (*vbuf)[D_][64] = (__bf16 (*)[D_][64])(arena + 16384);
    float  (*vred)[64]     = (float  (*)[64])(arena + 32768);

    const size_t base = (size_t)bh * S_ * D_;
    const float* Qb = Q + base;
    const float* Kb = K + base;
    const float* Vb = V + base;
    const int vofs = (par == 0) ? D_ : -D_;            // opp-parity row offset

    // ---- Q as QK B-operand fragments (st = K·Q^T): B[n=query l15][k=d]
    bf16x8 qf[2][2];                 // [qt2][ks]
    #pragma unroll
    for (int qt2 = 0; qt2 < 2; ++qt2) {
        const int qrow = qt * BQ + wave * 32 + qt2 * 16 + l15;
        const float* qsrc = Qb + (size_t)(par + 2 * qrow) * D_ + quad * 8;
        #pragma unroll
        for (int ks = 0; ks < 2; ++ks) {
            const float4 a = *(const float4*)(qsrc + ks * 32);
            const float4 b = *(const float4*)(qsrc + ks * 32 + 4);
            bf16x8 w;
            w[0] = (__bf16)(a.x * QSCALE); w[1] = (__bf16)(a.y * QSCALE);
            w[2] = (__bf16)(a.z * QSCALE); w[3] = (__bf16)(a.w * QSCALE);
            w[4] = (__bf16)(b.x * QSCALE); w[5] = (__bf16)(b.y * QSCALE);
            w[6] = (__bf16)(b.z * QSCALE); w[7] = (__bf16)(b.w * QSCALE);
            qf[qt2][ks] = w;
        }
    }

    // staging decomposition (256 threads):
    //   K: rows i*32+(tid>>3), chunk tid&7; V: column lane, key-chunks wave, wave+4
    const int kr0 = tid >> 3;
    const int kc8 = tid & 7;

    float4 pka[2], pkb[2];
    float  pv[16], pvo[16];

    auto issue_loads = [&](int kt) {
        #pragma unroll
        for (int i = 0; i < 2; ++i) {
            const int r = i * 32 + kr0;
            const float* ksrc = Kb + (size_t)(par + 2 * (kt * BK + r)) * D_ + kc8 * 8;
            pka[i] = *(const float4*)ksrc;
            pkb[i] = *(const float4*)(ksrc + 4);
        }
        #pragma unroll
        for (int i = 0; i < 2; ++i) {
            const int c = wave + 4 * i;
            const float* vsrc = Vb + (size_t)(par + 2 * (kt * BK + c * 8)) * D_ + lane;
            #pragma unroll
            for (int j = 0; j < 8; ++j) {
                pv [i * 8 + j] = vsrc[(size_t)(2 * j) * D_];
                pvo[i * 8 + j] = vsrc[(size_t)(2 * j) * D_ + vofs];
            }
        }
    };

    float vo = 0.f;                  // opp-parity Vsum partial, column d = lane
    auto stage = [&](int buf) {
        #pragma unroll
        for (int i = 0; i < 2; ++i) {
            const int r = i * 32 + kr0;
            bf16x8 w;
            w[0] = (__bf16)pka[i].x; w[1] = (__bf16)pka[i].y;
            w[2] = (__bf16)pka[i].z; w[3] = (__bf16)pka[i].w;
            w[4] = (__bf16)pkb[i].x; w[5] = (__bf16)pkb[i].y;
            w[6] = (__bf16)pkb[i].z; w[7] = (__bf16)pkb[i].w;
            *(bf16x8*)&kbuf[buf][r][KSW(r, kc8)] = w;
        }
        #pragma unroll
        for (int i = 0; i < 2; ++i) {
            const int c = wave + 4 * i;
            bf16x8 w;
            #pragma unroll
            for (int j = 0; j < 8; ++j) w[j] = (__bf16)pv[i * 8 + j];
            *(bf16x8*)&vbuf[buf][lane][KSW(lane, c)] = w;
            vo += ((pvo[i*8+0] + pvo[i*8+1]) + (pvo[i*8+2] + pvo[i*8+3]))
                + ((pvo[i*8+4] + pvo[i*8+5]) + (pvo[i*8+6] + pvo[i*8+7]));
        }
    };

    issue_loads(0);
    stage(0);
    __syncthreads();

    // O^T accumulators: C[m=d=quad*4+r (+16dt)][n=query=l15], per qt2
    f32x4 acc[2][4];
    #pragma unroll
    for (int q2 = 0; q2 < 2; ++q2)
        #pragma unroll
        for (int dt = 0; dt < 4; ++dt) acc[q2][dt] = (f32x4){0.f, 0.f, 0.f, 0.f};
    float l_acc[2] = {0.f, 0.f};     // per-lane partial Z for query l15 (per qt2)

    for (int kt = 0; kt < NKT; ++kt) {
        const int cur = kt & 1;
        const bool pf = (kt + 1 < NKT);

        if (pf) issue_loads(kt + 1);   // latency overlaps compute below

        const __bf16 (*kb)[64] = kbuf[cur];
        const __bf16 (*vb)[64] = vbuf[cur];

        // ---- K A-fragments for QK (K=32): 8 b128
        bf16x8 ka[2][4];
        #pragma unroll
        for (int ks = 0; ks < 2; ++ks)
            #pragma unroll
            for (int kt4 = 0; kt4 < 4; ++kt4) {
                const int R = kt4 * 16 + l15;
                ka[ks][kt4] = *(const bf16x8*)&kb[R][KSW(R, ks * 4 + quad)];
            }
        // ---- V^T A-fragments for PV (K=16): A[m=d l15][k=key quad*4+j], 16 b64
        bf16x4 va[4][4];             // [kt4][dt]
        #pragma unroll
        for (int dt = 0; dt < 4; ++dt) {
            const int R = dt * 16 + l15;
            const int ro = R & 7;
            #pragma unroll
            for (int kt4 = 0; kt4 < 4; ++kt4) {
                const int ch = (kt4 * 2 + (quad >> 1)) ^ ro;
                va[kt4][dt] = *(const bf16x4*)&vb[R][ch * 8 + (quad & 1) * 4];
            }
        }

        // ---- st = K·Q^T, p = exp2(st) -> P B-frag in regs -> PV directly
        #pragma unroll
        for (int qt2 = 0; qt2 < 2; ++qt2) {
            f32x4 st[4];
            #pragma unroll
            for (int kt4 = 0; kt4 < 4; ++kt4) st[kt4] = (f32x4){0.f, 0.f, 0.f, 0.f};
            #pragma unroll
            for (int ks = 0; ks < 2; ++ks)
                #pragma unroll
                for (int kt4 = 0; kt4 < 4; ++kt4)
                    st[kt4] = __builtin_amdgcn_mfma_f32_16x16x32_bf16(
                        ka[ks][kt4], qf[qt2][ks], st[kt4], 0, 0, 0);
            #pragma unroll
            for (int kt4 = 0; kt4 < 4; ++kt4) {
                const float p0 = EXP2(st[kt4][0]);
                const float p1 = EXP2(st[kt4][1]);
                const float p2 = EXP2(st[kt4][2]);
                const float p3 = EXP2(st[kt4][3]);
                l_acc[qt2] += (p0 + p1) + (p2 + p3);
                bf16x4 pb;
                pb[0] = (__bf16)p0; pb[1] = (__bf16)p1;
                pb[2] = (__bf16)p2; pb[3] = (__bf16)p3;
                #pragma unroll
                for (int dt = 0; dt < 4; ++dt)
                    acc[qt2][dt] = mfma16(va[kt4][dt], pb, acc[qt2][dt]);
            }
        }

        if (pf) stage(1 - cur);
        __syncthreads();
    }

    // ---- cross-wave reduction of opp-parity Vsum (vred is outside buffers)
    vred[wave][lane] = vo;
    __syncthreads();

    // vso per dt as f32x4 over r (d = dt*16 + quad*4 + r); read BEFORE the
    // transpose tiles (which reuse the kbuf/vbuf arena) are written.
    f32x4 vs4[4];
    #pragma unroll
    for (int dt = 0; dt < 4; ++dt) {
        f32x4 s = (f32x4){0.f, 0.f, 0.f, 0.f};
        #pragma unroll
        for (int w = 0; w < NW; ++w)
            s += *(const f32x4*)&vred[w][dt * 16 + quad * 4];
        vs4[dt] = s;
    }
    // Z per query l15 (lane-local after quad fold) — applies per-lane to O^T cols
    float rz[2];
    #pragma unroll
    for (int qt2 = 0; qt2 < 2; ++qt2) {
        float Z = l_acc[qt2];
        Z += __shfl_xor(Z, 16);
        Z += __shfl_xor(Z, 32);
        rz[qt2] = 1.0f / (Z + 1024.0f);
    }

    // ---- epilogue transpose: per-wave private f32 tile [16 q][68 d] in arena
    float* tw = (float*)arena + wave * (16 * 68);
    #pragma unroll
    for (int qt2 = 0; qt2 < 2; ++qt2) {
        #pragma unroll
        for (int dt = 0; dt < 4; ++dt) {
            const f32x4 o = (acc[qt2][dt] + vs4[dt]) * rz[qt2];
            *(f32x4*)&tw[l15 * 68 + dt * 16 + quad * 4] = o;
        }
        // per-wave private + in-order DS pipe: no barrier needed
        #pragma unroll
        for (int i = 0; i < 4; ++i) {
            const int q = i * 4 + quad;
            const f32x4 ov = *(const f32x4*)&tw[q * 68 + l15 * 4];
            const int qg = par + 2 * (qt * BQ + wave * 32 + qt2 * 16 + q);
            *(f32x4*)&out[base + (size_t)qg * D_ + l15 * 4] = ov;
        }
    }
}

extern "C" void kernel_launch(void* const* d_in, const int* in_sizes, int n_in,
                              void* d_out, int out_size, void* d_ws, size_t ws_size,
                              hipStream_t stream) {
    const float* Q = (const float*)d_in[0];
    const float* K = (const float*)d_in[1];
    const float* V = (const float*)d_in[2];
    float* out = (float*)d_out;
    attn_kernel<<<dim3(B_ * H_, 2, SP_ / BQ), dim3(256), 0, stream>>>(Q, K, V, out);
}